// Round 6
// baseline (153.988 us; speedup 1.0000x reference)
//
#include <hip/hip_runtime.h>
#include <math.h>

#define NH   32
#define NKVH 8
#define HD   64
#define WIN  256
#define BB   2
#define SS   2048

typedef short short8 __attribute__((ext_vector_type(8)));
typedef float f32x4  __attribute__((ext_vector_type(4)));

__device__ __forceinline__ ushort f2bf(float x) {
    union { float f; unsigned u; } v; v.f = x;
    unsigned u = v.u + 0x7FFF + ((v.u >> 16) & 1);   // RNE
    return (ushort)(u >> 16);
}

__device__ __forceinline__ int cvtpk_bf16(float lo, float hi) {
    int r;
    asm("v_cvt_pk_bf16_f32 %0, %1, %2" : "=v"(r) : "v"(lo), "v"(hi));
    return r;
}

// XOR-swizzle within a 4KB chunk image (bits 4-6 ^= bits 7-9).
// Applied at ds_write AND ds_read -> both-sides rule, bank-spread reads.
__device__ __forceinline__ int swz(int L) { return L ^ (((L >> 7) & 7) << 4); }

// ---- fully fused: RoPE(K) + V-transpose staged straight into LDS, no prep
// kernel, no workspace. Block = 4 waves = 4 GQA heads of one kvh; K/V chunk
// staged once per block (reg-stage -> RoPE/pack -> swizzled ds_write),
// double-buffered, loads issued at iter-top (latency hidden under compute).
__global__ __launch_bounds__(256, 4) void attn_fused(const float* __restrict__ Q,
                                                     const float* __restrict__ K,
                                                     const float* __restrict__ V,
                                                     float* __restrict__ O) {
    __shared__ __align__(16) ushort ldsK[2][2048];   // [key%32][d] bf16, swizzled
    __shared__ __align__(16) ushort ldsV[2][2048];   // [d][key%32] bf16, swizzled
    const int tid = threadIdx.x;
    const int wv = tid >> 6, lane = tid & 63;
    const int lo16 = lane & 15, quad = lane >> 4;
    // bijective XCD swizzle: 1024 wg = 8 XCD * 128 contiguous
    const int bidx = (blockIdx.x & 7) * 128 + (blockIdx.x >> 3);
    const int qblk = bidx & 63;
    const int kvh  = (bidx >> 6) & 7;
    const int b    = bidx >> 9;
    const int h    = kvh * 4 + wv;
    const int q0   = qblk * 32;

    // staging roles
    const int skey = tid >> 3, sdg = tid & 7;        // K: key 0..31, d = sdg*8..+7
    const int skp  = tid & 15, sdq = tid >> 4;       // V: keys 2skp,2skp+1, d = sdq*4..+3
    const float kratio = 0.74989420933f;             // 10000^(-1/32)
    const float kinv0  = __powf(10000.f, -(float)((sdg & 3) * 8) * (1.f / 32.f));

    float kx[8]; float4 va, vc;
#define LOADCHUNK(cidx) do {                                                          \
        const float* krow_ = K + (size_t)(b * SS + (cidx) * 32 + skey) * (NKVH * HD)  \
                               + kvh * HD + sdg * 8;                                  \
        *(float4*)(kx)     = *(const float4*)(krow_);                                 \
        *(float4*)(kx + 4) = *(const float4*)(krow_ + 4);                             \
        const float* vrow_ = V + (size_t)(b * SS + (cidx) * 32 + 2 * skp) * (NKVH * HD)\
                               + kvh * HD + sdq * 4;                                  \
        va = *(const float4*)(vrow_);                                                 \
        vc = *(const float4*)(vrow_ + NKVH * HD);                                     \
    } while (0)

#define ROPEWRITE(kb_, buf_) do {                                                     \
        int s_ = (kb_) + skey;                                                        \
        float inv_ = kinv0;                                                           \
        ushort out_[8];                                                               \
        _Pragma("unroll")                                                             \
        for (int j = 0; j < 8; ++j) {                                                 \
            float partner_ = __shfl(kx[j], (tid & 63) ^ 4, 64);   /* d ^ 32 */        \
            float sn_, cs_;                                                           \
            __sincosf((float)s_ * inv_, &sn_, &cs_);                                  \
            out_[j] = f2bf(kx[j] * cs_ + ((sdg < 4) ? -partner_ : partner_) * sn_);   \
            inv_ *= kratio;                                                           \
        }                                                                             \
        *(short8*)((char*)&ldsK[buf_][0] + swz(skey * 128 + sdg * 16)) = *(short8*)out_;\
        _Pragma("unroll")                                                             \
        for (int j = 0; j < 4; ++j) {                                                 \
            int d_ = sdq * 4 + j;                                                     \
            unsigned w_ = (unsigned)f2bf(((const float*)&va)[j])                      \
                        | ((unsigned)f2bf(((const float*)&vc)[j]) << 16);             \
            *(unsigned*)((char*)&ldsV[buf_][0] + swz(d_ * 64 + skp * 4)) = w_;        \
        }                                                                             \
    } while (0)

    float invf[8];
#pragma unroll
    for (int j = 0; j < 8; ++j)
        invf[j] = __powf(10000.f, -(float)(quad * 8 + j) * (1.f / 32.f));

    // Q load + RoPE + scale -> MFMA B-operand-shaped regs
    short8 aq[2][2];
#pragma unroll
    for (int t = 0; t < 2; ++t) {
        int qi = q0 + t * 16 + lo16;
        const float* qrow = Q + (size_t)(b * SS + qi) * (NH * HD) + h * HD;
        float lo[8], hi[8];
        *(float4*)(lo)     = *(const float4*)(qrow + quad * 8);
        *(float4*)(lo + 4) = *(const float4*)(qrow + quad * 8 + 4);
        *(float4*)(hi)     = *(const float4*)(qrow + 32 + quad * 8);
        *(float4*)(hi + 4) = *(const float4*)(qrow + 32 + quad * 8 + 4);
#pragma unroll
        for (int j = 0; j < 8; ++j) {
            float sn, cs;
            __sincosf((float)qi * invf[j], &sn, &cs);
            aq[t][0][j] = (short)f2bf((lo[j] * cs - hi[j] * sn) * 0.125f);
            aq[t][1][j] = (short)f2bf((hi[j] * cs + lo[j] * sn) * 0.125f);
        }
    }

    f32x4 acc[2][4];
#pragma unroll
    for (int t = 0; t < 2; ++t)
#pragma unroll
        for (int i = 0; i < 4; ++i) acc[t][i] = (f32x4){0.f, 0.f, 0.f, 0.f};
    float psum[2] = {0.f, 0.f};

    // ds_bpermute byte indices for the P quad-exchange
    const int idxAB = (lo16 + ((quad & 1) << 5)) << 2;   // src quad {0,2,0,2}
    const int idxCD = idxAB + 64;                        // src quad {1,3,1,3}
    const bool hiq  = quad >= 2;

    int klo = q0 - WIN; if (klo < 0) klo = 0;
    const int c0  = klo >> 5;
    const int cnt = (q0 >> 5) - c0 + 1;      // chunks in window (1..9)

    // prologue: stage chunk c0 into buf 0
    LOADCHUNK(c0);
    ROPEWRITE(klo, 0);
    __syncthreads();

    int nb = 0;
    for (int it = 0; it < cnt; ++it, nb ^= 1) {
        const int kb = klo + it * 32;
        // issue next chunk's global loads now; consumed after compute (T14 split)
        if (it + 1 < cnt) LOADCHUNK(c0 + it + 1);

        // K fragments from swizzled LDS
        const char* kl = (const char*)&ldsK[nb][0];
        short8 k0 = *(const short8*)(kl + swz(lo16 * 128 + quad * 16));
        short8 k1 = *(const short8*)(kl + swz(lo16 * 128 + 64 + quad * 16));
        short8 k2 = *(const short8*)(kl + swz((lo16 + 16) * 128 + quad * 16));
        short8 k3 = *(const short8*)(kl + swz((lo16 + 16) * 128 + 64 + quad * 16));

        const f32x4 z = {0.f, 0.f, 0.f, 0.f};
        // S^T = K·Q^T : C[row=key(quad*4+r)][col=query(lo16)]
        __builtin_amdgcn_s_setprio(1);
        f32x4 s00 = __builtin_amdgcn_mfma_f32_16x16x32_bf16(k0, aq[0][0], z,   0, 0, 0);
        s00       = __builtin_amdgcn_mfma_f32_16x16x32_bf16(k1, aq[0][1], s00, 0, 0, 0);
        f32x4 s01 = __builtin_amdgcn_mfma_f32_16x16x32_bf16(k2, aq[0][0], z,   0, 0, 0);
        s01       = __builtin_amdgcn_mfma_f32_16x16x32_bf16(k3, aq[0][1], s01, 0, 0, 0);
        f32x4 s10 = __builtin_amdgcn_mfma_f32_16x16x32_bf16(k0, aq[1][0], z,   0, 0, 0);
        s10       = __builtin_amdgcn_mfma_f32_16x16x32_bf16(k1, aq[1][1], s10, 0, 0, 0);
        f32x4 s11 = __builtin_amdgcn_mfma_f32_16x16x32_bf16(k2, aq[1][0], z,   0, 0, 0);
        s11       = __builtin_amdgcn_mfma_f32_16x16x32_bf16(k3, aq[1][1], s11, 0, 0, 0);
        __builtin_amdgcn_s_setprio(0);

        // softmax numerator + in-register P transform to PV A-frag layout
        short8 ap[2];
#pragma unroll
        for (int t = 0; t < 2; ++t) {
            const f32x4 sa = t ? s10 : s00;
            const f32x4 sb = t ? s11 : s01;
            const int qtmin = q0 + t * 16;
            const int myq   = qtmin + lo16;
            float p[8];
            if ((kb + 31 > qtmin) || (kb < qtmin + 15 - WIN)) {   // boundary chunk: mask
#pragma unroll
                for (int r = 0; r < 4; ++r) {
                    int key0 = kb + quad * 4 + r;
                    int key1 = key0 + 16;
                    p[r]     = (key0 <= myq && key0 >= myq - WIN) ? __expf(sa[r]) : 0.f;
                    p[4 + r] = (key1 <= myq && key1 >= myq - WIN) ? __expf(sb[r]) : 0.f;
                }
            } else {                                              // interior: no mask
#pragma unroll
                for (int r = 0; r < 4; ++r) { p[r] = __expf(sa[r]); p[4 + r] = __expf(sb[r]); }
            }
            psum[t] += ((p[0] + p[1]) + (p[2] + p[3])) + ((p[4] + p[5]) + (p[6] + p[7]));

            // lane holds keys {4q..4q+3, 16+4q..16+4q+3} for query lo16;
            // A-frag needs keys {8q..8q+7} for query lo16 -> cross-quad pull.
            int w0 = cvtpk_bf16(p[0], p[1]);
            int w1 = cvtpk_bf16(p[2], p[3]);
            int w2 = cvtpk_bf16(p[4], p[5]);
            int w3 = cvtpk_bf16(p[6], p[7]);
            int a0 = __builtin_amdgcn_ds_bpermute(idxAB, w0);
            int a2 = __builtin_amdgcn_ds_bpermute(idxAB, w2);
            int b1 = __builtin_amdgcn_ds_bpermute(idxAB, w1);
            int b3 = __builtin_amdgcn_ds_bpermute(idxAB, w3);
            int cc0 = __builtin_amdgcn_ds_bpermute(idxCD, w0);
            int cc2 = __builtin_amdgcn_ds_bpermute(idxCD, w2);
            int d1 = __builtin_amdgcn_ds_bpermute(idxCD, w1);
            int d3 = __builtin_amdgcn_ds_bpermute(idxCD, w3);
            union { int i[4]; short8 s; } u;
            u.i[0] = hiq ? a2  : a0;    // keys 8q+0,1
            u.i[1] = hiq ? b3  : b1;    // keys 8q+2,3
            u.i[2] = hiq ? cc2 : cc0;   // keys 8q+4,5
            u.i[3] = hiq ? d3  : d1;    // keys 8q+6,7
            ap[t] = u.s;
        }

        // V fragments from swizzled LDS
        const char* vl = (const char*)&ldsV[nb][0];
        short8 vf[4];
#pragma unroll
        for (int i = 0; i < 4; ++i)
            vf[i] = *(const short8*)(vl + swz((i * 16 + lo16) * 64 + quad * 16));

        __builtin_amdgcn_s_setprio(1);
#pragma unroll
        for (int i = 0; i < 4; ++i)
            acc[0][i] = __builtin_amdgcn_mfma_f32_16x16x32_bf16(ap[0], vf[i], acc[0][i], 0, 0, 0);
#pragma unroll
        for (int i = 0; i < 4; ++i)
            acc[1][i] = __builtin_amdgcn_mfma_f32_16x16x32_bf16(ap[1], vf[i], acc[1][i], 0, 0, 0);
        __builtin_amdgcn_s_setprio(0);

        // stage next chunk into the other buffer (regs were loaded at iter top)
        if (it + 1 < cnt) ROPEWRITE(kb + 32, nb ^ 1);

        __syncthreads();   // writes to nb^1 visible; reads of nb done before reuse
    }

#pragma unroll
    for (int t = 0; t < 2; ++t) {
        float ps = psum[t];
        ps += __shfl_xor(ps, 16, 64);
        ps += __shfl_xor(ps, 32, 64);        // all lanes: total for query lo16
#pragma unroll
        for (int r = 0; r < 4; ++r) {
            float invr = 1.f / __shfl(ps, quad * 4 + r, 16);
            int qr = q0 + t * 16 + quad * 4 + r;
            size_t orow = ((size_t)(b * SS + qr) * NH + h) * HD;
            O[orow + 0 * 16 + lo16] = acc[t][0][r] * invr;
            O[orow + 1 * 16 + lo16] = acc[t][1][r] * invr;
            O[orow + 2 * 16 + lo16] = acc[t][2][r] * invr;
            O[orow + 3 * 16 + lo16] = acc[t][3][r] * invr;
        }
    }
#undef LOADCHUNK
#undef ROPEWRITE
}

extern "C" void kernel_launch(void* const* d_in, const int* in_sizes, int n_in,
                              void* d_out, int out_size, void* d_ws, size_t ws_size,
                              hipStream_t stream) {
    const float* Q = (const float*)d_in[0];
    const float* K = (const float*)d_in[1];
    const float* V = (const float*)d_in[2];
    float* O = (float*)d_out;
    (void)d_ws; (void)ws_size;   // workspace-free: single fused dispatch

    attn_fused<<<BB * NKVH * (SS / 32), 256, 0, stream>>>(Q, K, V, O);
}

// Round 7
// 114.563 us; speedup vs baseline: 1.3441x; 1.3441x over previous
//
#include <hip/hip_runtime.h>
#include <math.h>

#define NH   32
#define NKVH 8
#define HD   64
#define WIN  256
#define BB   2
#define SS   2048

typedef short short8 __attribute__((ext_vector_type(8)));
typedef float f32x4  __attribute__((ext_vector_type(4)));

__device__ __forceinline__ ushort f2bf(float x) {
    union { float f; unsigned u; } v; v.f = x;
    unsigned u = v.u + 0x7FFF + ((v.u >> 16) & 1);   // RNE
    return (ushort)(u >> 16);
}

__device__ __forceinline__ int cvtpk_bf16(float lo, float hi) {
    int r;
    asm("v_cvt_pk_bf16_f32 %0, %1, %2" : "=v"(r) : "v"(lo), "v"(hi));
    return r;
}

// XOR-swizzle within a 4KB chunk (bits 4-6 ^= bits 7-9). Applied at prep-store
// AND lds-read; global_load_lds stages linearly so LDS holds the same image.
__device__ __forceinline__ int swz(int L) { return L ^ (((L >> 7) & 7) << 4); }

__device__ __forceinline__ void stage16(const void* g, void* l) {
    __builtin_amdgcn_global_load_lds(
        (const __attribute__((address_space(1))) unsigned int*)g,
        (__attribute__((address_space(3))) unsigned int*)l, 16, 0, 0);
}

// ---- fused pre-pass (R5, verified): swizzled 4KB chunk images via LDS,
// coalesced dwordx4 copy-out.
// Kr chunk (4KB): [key%32][d] bf16 rows of 128B, XOR-swizzled.
// Vt chunk (4KB): [d][key%32] bf16 rows of 64B,  XOR-swizzled.
__global__ __launch_bounds__(256) void prep_kv(const float* __restrict__ K,
                                               const float* __restrict__ V,
                                               ushort* __restrict__ Kr,
                                               ushort* __restrict__ Vt) {
    __shared__ __align__(16) ushort ldsK[2048];
    __shared__ __align__(16) ushort ldsV[2048];
    const int bidx = blockIdx.x;                // (b, kvh, sblk): 2*8*64
    const int sblk = bidx & 63;
    const int s0   = sblk * 32;
    const int kvh  = (bidx >> 6) & 7;
    const int b    = bidx >> 9;
    const int tid  = threadIdx.x;

    {
        const int key = tid >> 3, dg = tid & 7;
        const int s   = s0 + key;
        const float* krow = K + (size_t)(b * SS + s) * (NKVH * HD) + kvh * HD + dg * 8;
        float x[8];
        *(float4*)(x)     = *(const float4*)(krow);
        *(float4*)(x + 4) = *(const float4*)(krow + 4);
        float inv = __powf(10000.f, -(float)((dg & 3) * 8) * (1.f / 32.f));
        const float ratio = 0.74989420933f;      // 10000^(-1/32)
        ushort out[8];
#pragma unroll
        for (int j = 0; j < 8; ++j) {
            float partner = __shfl(x[j], (tid & 63) ^ 4, 64);   // d ^ 32 holder
            float sn, cs;
            __sincosf((float)s * inv, &sn, &cs);
            out[j] = f2bf(x[j] * cs + ((dg < 4) ? -partner : partner) * sn);
            inv *= ratio;
        }
        *(short8*)((char*)ldsK + swz(key * 128 + dg * 16)) = *(short8*)out;
    }
    {
        const int kp = tid & 15, dq = tid >> 4;
        const float* v0 = V + (size_t)(b * SS + s0 + 2 * kp) * (NKVH * HD) + kvh * HD + dq * 4;
        float4 a = *(const float4*)v0;
        float4 c = *(const float4*)(v0 + NKVH * HD);
#pragma unroll
        for (int j = 0; j < 4; ++j) {
            int d = dq * 4 + j;
            unsigned w = (unsigned)f2bf(((const float*)&a)[j])
                       | ((unsigned)f2bf(((const float*)&c)[j]) << 16);
            *(unsigned*)((char*)ldsV + swz(d * 64 + kp * 4)) = w;
        }
    }
    __syncthreads();
    char* kc = (char*)(Kr + (size_t)(b * NKVH + kvh) * SS * HD) + (size_t)sblk * 4096;
    char* vc = (char*)(Vt + (size_t)(b * NKVH + kvh) * HD * SS) + (size_t)sblk * 4096;
    *(short8*)(kc + tid * 16) = *(short8*)((char*)ldsK + tid * 16);
    *(short8*)(vc + tid * 16) = *(short8*)((char*)ldsV + tid * 16);
}

// ---- main v7: 64-key double-chunk iterations, raw s_barrier + counted vmcnt.
// Block = 4 waves = 4 GQA heads of one kvh; K/V pair staged once per block,
// double-buffered 2-pair LDS; staging never drains to vmcnt(0) in the loop.
__global__ __launch_bounds__(256, 4) void attn_mfma(const float* __restrict__ Q,
                                                    const ushort* __restrict__ Kr,
                                                    const ushort* __restrict__ Vt,
                                                    float* __restrict__ O) {
    __shared__ __align__(16) ushort ldsK[2][2][2048];   // [buf][slot][chunk image]
    __shared__ __align__(16) ushort ldsV[2][2][2048];
    const int wv = threadIdx.x >> 6, lane = threadIdx.x & 63;
    const int lo16 = lane & 15, quad = lane >> 4;
    // bijective XCD swizzle: 1024 wg = 8 XCD * 128 contiguous
    const int bidx = (blockIdx.x & 7) * 128 + (blockIdx.x >> 3);
    const int qblk = bidx & 63;
    const int kvh  = (bidx >> 6) & 7;
    const int b    = bidx >> 9;
    const int h    = kvh * 4 + wv;
    const int q0   = qblk * 32;

    float invf[8];
#pragma unroll
    for (int j = 0; j < 8; ++j)
        invf[j] = __powf(10000.f, -(float)(quad * 8 + j) * (1.f / 32.f));

    // Q load + RoPE + scale -> MFMA B-operand-shaped regs
    short8 aq[2][2];
#pragma unroll
    for (int t = 0; t < 2; ++t) {
        int qi = q0 + t * 16 + lo16;
        const float* qrow = Q + (size_t)(b * SS + qi) * (NH * HD) + h * HD;
        float lo[8], hi[8];
        *(float4*)(lo)     = *(const float4*)(qrow + quad * 8);
        *(float4*)(lo + 4) = *(const float4*)(qrow + quad * 8 + 4);
        *(float4*)(hi)     = *(const float4*)(qrow + 32 + quad * 8);
        *(float4*)(hi + 4) = *(const float4*)(qrow + 32 + quad * 8 + 4);
#pragma unroll
        for (int j = 0; j < 8; ++j) {
            float sn, cs;
            __sincosf((float)qi * invf[j], &sn, &cs);
            aq[t][0][j] = (short)f2bf((lo[j] * cs - hi[j] * sn) * 0.125f);
            aq[t][1][j] = (short)f2bf((hi[j] * cs + lo[j] * sn) * 0.125f);
        }
    }

    const char* kbase = (const char*)(Kr + (size_t)(b * NKVH + kvh) * SS * HD);
    const char* vbase = (const char*)(Vt + (size_t)(b * NKVH + kvh) * HD * SS);

    f32x4 acc[2][4];
#pragma unroll
    for (int t = 0; t < 2; ++t)
#pragma unroll
        for (int i = 0; i < 4; ++i) acc[t][i] = (f32x4){0.f, 0.f, 0.f, 0.f};
    float psum[2] = {0.f, 0.f};

    // ds_bpermute byte indices for the P quad-exchange
    const int idxAB = (lo16 + ((quad & 1) << 5)) << 2;   // src quad {0,2,0,2}
    const int idxCD = idxAB + 64;                        // src quad {1,3,1,3}
    const bool hiq  = quad >= 2;

    int klo = q0 - WIN; if (klo < 0) klo = 0;
    const int c0  = klo >> 5;
    const int cnt = (q0 >> 5) - c0 + 1;      // chunks in window (1..9)
    const int npairs = (cnt + 1) >> 1;

    // stage one 64-key pair (2 chunks) into buf: 4 vm ops per wave
    auto stagepair = [&](int pidx, int buf) {
        int ca = c0 + 2 * pidx, cb = ca + 1;
        if (ca > SS / 32 - 1) ca = SS / 32 - 1;   // phantom clamp (harmless)
        if (cb > SS / 32 - 1) cb = SS / 32 - 1;
        stage16(kbase + (size_t)ca * 4096 + wv * 1024 + lane * 16,
                (char*)&ldsK[buf][0][0] + wv * 1024);
        stage16(vbase + (size_t)ca * 4096 + wv * 1024 + lane * 16,
                (char*)&ldsV[buf][0][0] + wv * 1024);
        stage16(kbase + (size_t)cb * 4096 + wv * 1024 + lane * 16,
                (char*)&ldsK[buf][1][0] + wv * 1024);
        stage16(vbase + (size_t)cb * 4096 + wv * 1024 + lane * 16,
                (char*)&ldsV[buf][1][0] + wv * 1024);
    };

    // per-chunk compute (identical machinery to R4/R5)
    auto compute = [&](int kb, const char* kl, const char* vl) {
        short8 k0 = *(const short8*)(kl + swz(lo16 * 128 + quad * 16));
        short8 k1 = *(const short8*)(kl + swz(lo16 * 128 + 64 + quad * 16));
        short8 k2 = *(const short8*)(kl + swz((lo16 + 16) * 128 + quad * 16));
        short8 k3 = *(const short8*)(kl + swz((lo16 + 16) * 128 + 64 + quad * 16));

        const f32x4 z = {0.f, 0.f, 0.f, 0.f};
        __builtin_amdgcn_s_setprio(1);
        f32x4 s00 = __builtin_amdgcn_mfma_f32_16x16x32_bf16(k0, aq[0][0], z,   0, 0, 0);
        s00       = __builtin_amdgcn_mfma_f32_16x16x32_bf16(k1, aq[0][1], s00, 0, 0, 0);
        f32x4 s01 = __builtin_amdgcn_mfma_f32_16x16x32_bf16(k2, aq[0][0], z,   0, 0, 0);
        s01       = __builtin_amdgcn_mfma_f32_16x16x32_bf16(k3, aq[0][1], s01, 0, 0, 0);
        f32x4 s10 = __builtin_amdgcn_mfma_f32_16x16x32_bf16(k0, aq[1][0], z,   0, 0, 0);
        s10       = __builtin_amdgcn_mfma_f32_16x16x32_bf16(k1, aq[1][1], s10, 0, 0, 0);
        f32x4 s11 = __builtin_amdgcn_mfma_f32_16x16x32_bf16(k2, aq[1][0], z,   0, 0, 0);
        s11       = __builtin_amdgcn_mfma_f32_16x16x32_bf16(k3, aq[1][1], s11, 0, 0, 0);
        __builtin_amdgcn_s_setprio(0);

        short8 ap[2];
#pragma unroll
        for (int t = 0; t < 2; ++t) {
            const f32x4 sa = t ? s10 : s00;
            const f32x4 sb = t ? s11 : s01;
            const int qtmin = q0 + t * 16;
            const int myq   = qtmin + lo16;
            float p[8];
            if ((kb + 31 > qtmin) || (kb < qtmin + 15 - WIN)) {   // boundary: mask
#pragma unroll
                for (int r = 0; r < 4; ++r) {
                    int key0 = kb + quad * 4 + r;
                    int key1 = key0 + 16;
                    p[r]     = (key0 <= myq && key0 >= myq - WIN) ? __expf(sa[r]) : 0.f;
                    p[4 + r] = (key1 <= myq && key1 >= myq - WIN) ? __expf(sb[r]) : 0.f;
                }
            } else {
#pragma unroll
                for (int r = 0; r < 4; ++r) { p[r] = __expf(sa[r]); p[4 + r] = __expf(sb[r]); }
            }
            psum[t] += ((p[0] + p[1]) + (p[2] + p[3])) + ((p[4] + p[5]) + (p[6] + p[7]));

            int w0 = cvtpk_bf16(p[0], p[1]);
            int w1 = cvtpk_bf16(p[2], p[3]);
            int w2 = cvtpk_bf16(p[4], p[5]);
            int w3 = cvtpk_bf16(p[6], p[7]);
            int a0 = __builtin_amdgcn_ds_bpermute(idxAB, w0);
            int a2 = __builtin_amdgcn_ds_bpermute(idxAB, w2);
            int b1 = __builtin_amdgcn_ds_bpermute(idxAB, w1);
            int b3 = __builtin_amdgcn_ds_bpermute(idxAB, w3);
            int cc0 = __builtin_amdgcn_ds_bpermute(idxCD, w0);
            int cc2 = __builtin_amdgcn_ds_bpermute(idxCD, w2);
            int d1 = __builtin_amdgcn_ds_bpermute(idxCD, w1);
            int d3 = __builtin_amdgcn_ds_bpermute(idxCD, w3);
            union { int i[4]; short8 s; } u;
            u.i[0] = hiq ? a2  : a0;
            u.i[1] = hiq ? b3  : b1;
            u.i[2] = hiq ? cc2 : cc0;
            u.i[3] = hiq ? d3  : d1;
            ap[t] = u.s;
        }

        short8 vf[4];
#pragma unroll
        for (int i = 0; i < 4; ++i)
            vf[i] = *(const short8*)(vl + swz((i * 16 + lo16) * 64 + quad * 16));

        __builtin_amdgcn_s_setprio(1);
#pragma unroll
        for (int i = 0; i < 4; ++i)
            acc[0][i] = __builtin_amdgcn_mfma_f32_16x16x32_bf16(ap[0], vf[i], acc[0][i], 0, 0, 0);
#pragma unroll
        for (int i = 0; i < 4; ++i)
            acc[1][i] = __builtin_amdgcn_mfma_f32_16x16x32_bf16(ap[1], vf[i], acc[1][i], 0, 0, 0);
        __builtin_amdgcn_s_setprio(0);
    };

    // prologue: stage pair 0 into buf 0 (4 vm ops)
    stagepair(0, 0);

    int nb = 0;
    for (int p = 0; p < npairs; ++p, nb ^= 1) {
        stagepair(p + 1, nb ^ 1);                       // 4 new vm ops (phantom-clamped)
        asm volatile("s_waitcnt vmcnt(4)" ::: "memory"); // wait pair p (prev 4) only
        __builtin_amdgcn_s_barrier();                    // raw barrier, no drain
        __builtin_amdgcn_sched_barrier(0);               // no ds_read hoisting (rule #18)
        compute(klo + 2 * p * 32, (const char*)&ldsK[nb][0][0], (const char*)&ldsV[nb][0][0]);
        if (2 * p + 1 < cnt)
            compute(klo + (2 * p + 1) * 32, (const char*)&ldsK[nb][1][0], (const char*)&ldsV[nb][1][0]);
        __builtin_amdgcn_sched_barrier(0);
        __builtin_amdgcn_s_barrier();                    // all reads of nb done before overwrite
    }

#pragma unroll
    for (int t = 0; t < 2; ++t) {
        float ps = psum[t];
        ps += __shfl_xor(ps, 16, 64);
        ps += __shfl_xor(ps, 32, 64);        // all lanes: total for query lo16
#pragma unroll
        for (int r = 0; r < 4; ++r) {
            float invr = 1.f / __shfl(ps, quad * 4 + r, 16);
            int qr = q0 + t * 16 + quad * 4 + r;
            size_t orow = ((size_t)(b * SS + qr) * NH + h) * HD;
            O[orow + 0 * 16 + lo16] = acc[t][0][r] * invr;
            O[orow + 1 * 16 + lo16] = acc[t][1][r] * invr;
            O[orow + 2 * 16 + lo16] = acc[t][2][r] * invr;
            O[orow + 3 * 16 + lo16] = acc[t][3][r] * invr;
        }
    }
}

// ---------- fallback (no workspace): round-1 scalar kernel ----------
__device__ __forceinline__ float wave_sum(float x) {
#pragma unroll
    for (int off = 32; off > 0; off >>= 1) x += __shfl_xor(x, off, 64);
    return x;
}

__global__ __launch_bounds__(256) void attn_scalar(const float* __restrict__ Q,
                                                   const float* __restrict__ K,
                                                   const float* __restrict__ V,
                                                   float* __restrict__ O) {
    int wave = blockIdx.x * 4 + (threadIdx.x >> 6);
    int lane = threadIdx.x & 63;
    int q  = wave % SS;
    int bh = wave / SS;
    int h  = bh % NH;
    int b  = bh / NH;
    int kvh = h >> 2;

    float inv = __powf(10000.f, -(float)(lane & 31) * (1.f / 32.f));
    float sn, cs;
    __sincosf((float)q * inv, &sn, &cs);

    float qv = Q[(size_t)(b * SS + q) * (NH * HD) + h * HD + lane];
    float qpart = __shfl(qv, lane ^ 32, 64);
    float qrot = (qv * cs + ((lane < 32) ? -qpart : qpart) * sn) * 0.125f;

    const float* vbase = V + (size_t)b * SS * (NKVH * HD) + kvh * HD;
    float m = -1e30f, l = 0.f, acc = 0.f;
    int k0 = q - WIN; if (k0 < 0) k0 = 0;
    for (int k = k0; k <= q; ++k) {
        float kraw = K[(size_t)(b * SS + k) * (NKVH * HD) + kvh * HD + lane];
        float kpart = __shfl(kraw, lane ^ 32, 64);
        float ksn, kcs;
        __sincosf((float)k * inv, &ksn, &kcs);
        float kv = kraw * kcs + ((lane < 32) ? -kpart : kpart) * ksn;
        float vv = vbase[(size_t)k * (NKVH * HD) + lane];
        float score = wave_sum(qrot * kv);
        float mnew  = fmaxf(m, score);
        float alpha = __expf(m - mnew);
        float p     = __expf(score - mnew);
        l   = l * alpha + p;
        acc = acc * alpha + p * vv;
        m   = mnew;
    }
    O[(((size_t)(b * SS + q) * NH) + h) * HD + lane] = acc / l;
}

extern "C" void kernel_launch(void* const* d_in, const int* in_sizes, int n_in,
                              void* d_out, int out_size, void* d_ws, size_t ws_size,
                              hipStream_t stream) {
    const float* Q = (const float*)d_in[0];
    const float* K = (const float*)d_in[1];
    const float* V = (const float*)d_in[2];
    float* O = (float*)d_out;

    size_t kv_elems = (size_t)BB * NKVH * SS * HD;   // 2M elements
    size_t need = 2 * kv_elems * sizeof(ushort);     // 8 MB

    if (ws_size >= need) {
        ushort* Kr = (ushort*)d_ws;
        ushort* Vt = Kr + kv_elems;
        prep_kv<<<BB * NKVH * (SS / 32), 256, 0, stream>>>(K, V, Kr, Vt);
        attn_mfma<<<BB * NKVH * (SS / 32), 256, 0, stream>>>(Q, Kr, Vt, O);
    } else {
        attn_scalar<<<(BB * NH * SS) / 4, 256, 0, stream>>>(Q, K, V, O);
    }
}

// Round 8
// 113.077 us; speedup vs baseline: 1.3618x; 1.0131x over previous
//
#include <hip/hip_runtime.h>
#include <math.h>

#define NH   32
#define NKVH 8
#define HD   64
#define WIN  256
#define BB   2
#define SS   2048

typedef short short8 __attribute__((ext_vector_type(8)));
typedef float f32x4  __attribute__((ext_vector_type(4)));

__device__ __forceinline__ ushort f2bf(float x) {
    union { float f; unsigned u; } v; v.f = x;
    unsigned u = v.u + 0x7FFF + ((v.u >> 16) & 1);   // RNE
    return (ushort)(u >> 16);
}

__device__ __forceinline__ int cvtpk_bf16(float lo, float hi) {
    int r;
    asm("v_cvt_pk_bf16_f32 %0, %1, %2" : "=v"(r) : "v"(lo), "v"(hi));
    return r;
}

// XOR-swizzle within a 4KB chunk (bits 4-6 ^= bits 7-9). Applied at prep-store
// AND lds-read; global_load_lds stages linearly so LDS holds the same image.
__device__ __forceinline__ int swz(int L) { return L ^ (((L >> 7) & 7) << 4); }

__device__ __forceinline__ void stage16(const void* g, void* l) {
    __builtin_amdgcn_global_load_lds(
        (const __attribute__((address_space(1))) unsigned int*)g,
        (__attribute__((address_space(3))) unsigned int*)l, 16, 0, 0);
}

// ---- fused pre-pass: swizzled 4KB chunk images via LDS, coalesced copy-out.
// Kr chunk (4KB): [key%32][d] bf16 rows of 128B, XOR-swizzled.
// Vt chunk (4KB): [d][slot]  bf16 rows of 64B,  XOR-swizzled, where column
// slot holds key sigma(slot) = (slot>>3)*4 + (slot&3) + ((slot>>2)&1)*16.
// sigma makes QK^T's C-layout == PV's A-frag layout (no cross-lane exchange).
__global__ __launch_bounds__(256) void prep_kv(const float* __restrict__ K,
                                               const float* __restrict__ V,
                                               ushort* __restrict__ Kr,
                                               ushort* __restrict__ Vt) {
    __shared__ __align__(16) ushort ldsK[2048];
    __shared__ __align__(16) ushort ldsV[2048];
    const int bidx = blockIdx.x;                // (b, kvh, sblk): 2*8*64
    const int sblk = bidx & 63;
    const int s0   = sblk * 32;
    const int kvh  = (bidx >> 6) & 7;
    const int b    = bidx >> 9;
    const int tid  = threadIdx.x;

    {
        const int key = tid >> 3, dg = tid & 7;
        const int s   = s0 + key;
        const float* krow = K + (size_t)(b * SS + s) * (NKVH * HD) + kvh * HD + dg * 8;
        float x[8];
        *(float4*)(x)     = *(const float4*)(krow);
        *(float4*)(x + 4) = *(const float4*)(krow + 4);
        float inv = __powf(10000.f, -(float)((dg & 3) * 8) * (1.f / 32.f));
        const float ratio = 0.74989420933f;      // 10000^(-1/32)
        ushort out[8];
#pragma unroll
        for (int j = 0; j < 8; ++j) {
            float partner = __shfl(x[j], (tid & 63) ^ 4, 64);   // d ^ 32 holder
            float sn, cs;
            __sincosf((float)s * inv, &sn, &cs);
            out[j] = f2bf(x[j] * cs + ((dg < 4) ? -partner : partner) * sn);
            inv *= ratio;
        }
        *(short8*)((char*)ldsK + swz(key * 128 + dg * 16)) = *(short8*)out;
    }
    {
        const int kp = tid & 15, dq = tid >> 4;
        // slot pair (2kp, 2kp+1) holds keys (kf, kf+1) under sigma
        const int c  = 2 * kp;
        const int kf = ((c >> 3) * 4) + (c & 3) + (((c >> 2) & 1) * 16);
        const float* v0 = V + (size_t)(b * SS + s0 + kf) * (NKVH * HD) + kvh * HD + dq * 4;
        float4 a = *(const float4*)v0;
        float4 cvec = *(const float4*)(v0 + NKVH * HD);   // key kf+1
#pragma unroll
        for (int j = 0; j < 4; ++j) {
            int d = dq * 4 + j;
            unsigned w = (unsigned)f2bf(((const float*)&a)[j])
                       | ((unsigned)f2bf(((const float*)&cvec)[j]) << 16);
            *(unsigned*)((char*)ldsV + swz(d * 64 + kp * 4)) = w;
        }
    }
    __syncthreads();
    char* kc = (char*)(Kr + (size_t)(b * NKVH + kvh) * SS * HD) + (size_t)sblk * 4096;
    char* vc = (char*)(Vt + (size_t)(b * NKVH + kvh) * HD * SS) + (size_t)sblk * 4096;
    *(short8*)(kc + tid * 16) = *(short8*)((char*)ldsK + tid * 16);
    *(short8*)(vc + tid * 16) = *(short8*)((char*)ldsV + tid * 16);
}

// ---- main v8: sigma-permuted V => P feeds PV directly in-lane (no bpermute).
// Block = 4 waves = 4 GQA heads of one kvh; 64-key pair iterations, raw
// s_barrier + counted vmcnt (R7 schedule), double-buffered 2-pair LDS.
__global__ __launch_bounds__(256, 4) void attn_mfma(const float* __restrict__ Q,
                                                    const ushort* __restrict__ Kr,
                                                    const ushort* __restrict__ Vt,
                                                    float* __restrict__ O) {
    __shared__ __align__(16) ushort ldsK[2][2][2048];   // [buf][slot][chunk image]
    __shared__ __align__(16) ushort ldsV[2][2][2048];
    const int wv = threadIdx.x >> 6, lane = threadIdx.x & 63;
    const int lo16 = lane & 15, quad = lane >> 4;
    // bijective XCD swizzle: 1024 wg = 8 XCD * 128 contiguous
    const int bidx = (blockIdx.x & 7) * 128 + (blockIdx.x >> 3);
    const int qblk = bidx & 63;
    const int kvh  = (bidx >> 6) & 7;
    const int b    = bidx >> 9;
    const int h    = kvh * 4 + wv;
    const int q0   = qblk * 32;

    float invf[8];
#pragma unroll
    for (int j = 0; j < 8; ++j)
        invf[j] = __powf(10000.f, -(float)(quad * 8 + j) * (1.f / 32.f));

    // Q load + RoPE + scale -> MFMA B-operand-shaped regs
    short8 aq[2][2];
#pragma unroll
    for (int t = 0; t < 2; ++t) {
        int qi = q0 + t * 16 + lo16;
        const float* qrow = Q + (size_t)(b * SS + qi) * (NH * HD) + h * HD;
        float lo[8], hi[8];
        *(float4*)(lo)     = *(const float4*)(qrow + quad * 8);
        *(float4*)(lo + 4) = *(const float4*)(qrow + quad * 8 + 4);
        *(float4*)(hi)     = *(const float4*)(qrow + 32 + quad * 8);
        *(float4*)(hi + 4) = *(const float4*)(qrow + 32 + quad * 8 + 4);
#pragma unroll
        for (int j = 0; j < 8; ++j) {
            float sn, cs;
            __sincosf((float)qi * invf[j], &sn, &cs);
            aq[t][0][j] = (short)f2bf((lo[j] * cs - hi[j] * sn) * 0.125f);
            aq[t][1][j] = (short)f2bf((hi[j] * cs + lo[j] * sn) * 0.125f);
        }
    }

    const char* kbase = (const char*)(Kr + (size_t)(b * NKVH + kvh) * SS * HD);
    const char* vbase = (const char*)(Vt + (size_t)(b * NKVH + kvh) * HD * SS);

    f32x4 acc[2][4];
#pragma unroll
    for (int t = 0; t < 2; ++t)
#pragma unroll
        for (int i = 0; i < 4; ++i) acc[t][i] = (f32x4){0.f, 0.f, 0.f, 0.f};
    float psum[2] = {0.f, 0.f};

    int klo = q0 - WIN; if (klo < 0) klo = 0;
    const int c0  = klo >> 5;
    const int cnt = (q0 >> 5) - c0 + 1;      // chunks in window (1..9)
    const int npairs = (cnt + 1) >> 1;

    // stage one 64-key pair (2 chunks) into buf: 4 vm ops per wave
    auto stagepair = [&](int pidx, int buf) {
        int ca = c0 + 2 * pidx, cb = ca + 1;
        if (ca > SS / 32 - 1) ca = SS / 32 - 1;   // phantom clamp (harmless)
        if (cb > SS / 32 - 1) cb = SS / 32 - 1;
        stage16(kbase + (size_t)ca * 4096 + wv * 1024 + lane * 16,
                (char*)&ldsK[buf][0][0] + wv * 1024);
        stage16(vbase + (size_t)ca * 4096 + wv * 1024 + lane * 16,
                (char*)&ldsV[buf][0][0] + wv * 1024);
        stage16(kbase + (size_t)cb * 4096 + wv * 1024 + lane * 16,
                (char*)&ldsK[buf][1][0] + wv * 1024);
        stage16(vbase + (size_t)cb * 4096 + wv * 1024 + lane * 16,
                (char*)&ldsV[buf][1][0] + wv * 1024);
    };

    // per-chunk compute; P->PV hand-off is pure in-register now
    auto compute = [&](int kb, const char* kl, const char* vl) {
        short8 k0 = *(const short8*)(kl + swz(lo16 * 128 + quad * 16));
        short8 k1 = *(const short8*)(kl + swz(lo16 * 128 + 64 + quad * 16));
        short8 k2 = *(const short8*)(kl + swz((lo16 + 16) * 128 + quad * 16));
        short8 k3 = *(const short8*)(kl + swz((lo16 + 16) * 128 + 64 + quad * 16));

        const f32x4 z = {0.f, 0.f, 0.f, 0.f};
        __builtin_amdgcn_s_setprio(1);
        f32x4 s00 = __builtin_amdgcn_mfma_f32_16x16x32_bf16(k0, aq[0][0], z,   0, 0, 0);
        s00       = __builtin_amdgcn_mfma_f32_16x16x32_bf16(k1, aq[0][1], s00, 0, 0, 0);
        f32x4 s01 = __builtin_amdgcn_mfma_f32_16x16x32_bf16(k2, aq[0][0], z,   0, 0, 0);
        s01       = __builtin_amdgcn_mfma_f32_16x16x32_bf16(k3, aq[0][1], s01, 0, 0, 0);
        f32x4 s10 = __builtin_amdgcn_mfma_f32_16x16x32_bf16(k0, aq[1][0], z,   0, 0, 0);
        s10       = __builtin_amdgcn_mfma_f32_16x16x32_bf16(k1, aq[1][1], s10, 0, 0, 0);
        f32x4 s11 = __builtin_amdgcn_mfma_f32_16x16x32_bf16(k2, aq[1][0], z,   0, 0, 0);
        s11       = __builtin_amdgcn_mfma_f32_16x16x32_bf16(k3, aq[1][1], s11, 0, 0, 0);
        __builtin_amdgcn_s_setprio(0);

        short8 ap[2];
#pragma unroll
        for (int t = 0; t < 2; ++t) {
            const f32x4 sa = t ? s10 : s00;
            const f32x4 sb = t ? s11 : s01;
            const int qtmin = q0 + t * 16;
            const int myq   = qtmin + lo16;
            float p[8];
            if ((kb + 31 > qtmin) || (kb < qtmin + 15 - WIN)) {   // boundary: mask
#pragma unroll
                for (int r = 0; r < 4; ++r) {
                    int key0 = kb + quad * 4 + r;
                    int key1 = key0 + 16;
                    p[r]     = (key0 <= myq && key0 >= myq - WIN) ? __expf(sa[r]) : 0.f;
                    p[4 + r] = (key1 <= myq && key1 >= myq - WIN) ? __expf(sb[r]) : 0.f;
                }
            } else {
#pragma unroll
                for (int r = 0; r < 4; ++r) { p[r] = __expf(sa[r]); p[4 + r] = __expf(sb[r]); }
            }
            psum[t] += ((p[0] + p[1]) + (p[2] + p[3])) + ((p[4] + p[5]) + (p[6] + p[7]));

            // sigma-permuted V: lane's own keys {4q+r, 16+4q+r} ARE its A-frag
            // slots {8q..8q+7}; pack to bf16 pairs in-register, done.
            union { int i[4]; short8 s; } u;
            u.i[0] = cvtpk_bf16(p[0], p[1]);
            u.i[1] = cvtpk_bf16(p[2], p[3]);
            u.i[2] = cvtpk_bf16(p[4], p[5]);
            u.i[3] = cvtpk_bf16(p[6], p[7]);
            ap[t] = u.s;
        }

        short8 vf[4];
#pragma unroll
        for (int i = 0; i < 4; ++i)
            vf[i] = *(const short8*)(vl + swz((i * 16 + lo16) * 64 + quad * 16));

        __builtin_amdgcn_s_setprio(1);
#pragma unroll
        for (int i = 0; i < 4; ++i)
            acc[0][i] = __builtin_amdgcn_mfma_f32_16x16x32_bf16(ap[0], vf[i], acc[0][i], 0, 0, 0);
#pragma unroll
        for (int i = 0; i < 4; ++i)
            acc[1][i] = __builtin_amdgcn_mfma_f32_16x16x32_bf16(ap[1], vf[i], acc[1][i], 0, 0, 0);
        __builtin_amdgcn_s_setprio(0);
    };

    // prologue: stage pair 0 into buf 0 (4 vm ops)
    stagepair(0, 0);

    int nb = 0;
    for (int p = 0; p < npairs; ++p, nb ^= 1) {
        stagepair(p + 1, nb ^ 1);                       // 4 new vm ops (phantom-clamped)
        asm volatile("s_waitcnt vmcnt(4)" ::: "memory"); // wait pair p (prev 4) only
        __builtin_amdgcn_s_barrier();                    // raw barrier, no drain
        __builtin_amdgcn_sched_barrier(0);               // no ds_read hoisting (rule #18)
        compute(klo + 2 * p * 32, (const char*)&ldsK[nb][0][0], (const char*)&ldsV[nb][0][0]);
        if (2 * p + 1 < cnt)
            compute(klo + (2 * p + 1) * 32, (const char*)&ldsK[nb][1][0], (const char*)&ldsV[nb][1][0]);
        __builtin_amdgcn_sched_barrier(0);
        __builtin_amdgcn_s_barrier();                    // all reads of nb done before overwrite
    }

#pragma unroll
    for (int t = 0; t < 2; ++t) {
        float ps = psum[t];
        ps += __shfl_xor(ps, 16, 64);
        ps += __shfl_xor(ps, 32, 64);        // all lanes: total for query lo16
#pragma unroll
        for (int r = 0; r < 4; ++r) {
            float invr = 1.f / __shfl(ps, quad * 4 + r, 16);
            int qr = q0 + t * 16 + quad * 4 + r;
            size_t orow = ((size_t)(b * SS + qr) * NH + h) * HD;
            O[orow + 0 * 16 + lo16] = acc[t][0][r] * invr;
            O[orow + 1 * 16 + lo16] = acc[t][1][r] * invr;
            O[orow + 2 * 16 + lo16] = acc[t][2][r] * invr;
            O[orow + 3 * 16 + lo16] = acc[t][3][r] * invr;
        }
    }
}

// ---------- fallback (no workspace): round-1 scalar kernel ----------
__device__ __forceinline__ float wave_sum(float x) {
#pragma unroll
    for (int off = 32; off > 0; off >>= 1) x += __shfl_xor(x, off, 64);
    return x;
}

__global__ __launch_bounds__(256) void attn_scalar(const float* __restrict__ Q,
                                                   const float* __restrict__ K,
                                                   const float* __restrict__ V,
                                                   float* __restrict__ O) {
    int wave = blockIdx.x * 4 + (threadIdx.x >> 6);
    int lane = threadIdx.x & 63;
    int q  = wave % SS;
    int bh = wave / SS;
    int h  = bh % NH;
    int b  = bh / NH;
    int kvh = h >> 2;

    float inv = __powf(10000.f, -(float)(lane & 31) * (1.f / 32.f));
    float sn, cs;
    __sincosf((float)q * inv, &sn, &cs);

    float qv = Q[(size_t)(b * SS + q) * (NH * HD) + h * HD + lane];
    float qpart = __shfl(qv, lane ^ 32, 64);
    float qrot = (qv * cs + ((lane < 32) ? -qpart : qpart) * sn) * 0.125f;

    const float* vbase = V + (size_t)b * SS * (NKVH * HD) + kvh * HD;
    float m = -1e30f, l = 0.f, acc = 0.f;
    int k0 = q - WIN; if (k0 < 0) k0 = 0;
    for (int k = k0; k <= q; ++k) {
        float kraw = K[(size_t)(b * SS + k) * (NKVH * HD) + kvh * HD + lane];
        float kpart = __shfl(kraw, lane ^ 32, 64);
        float ksn, kcs;
        __sincosf((float)k * inv, &ksn, &kcs);
        float kv = kraw * kcs + ((lane < 32) ? -kpart : kpart) * ksn;
        float vv = vbase[(size_t)k * (NKVH * HD) + lane];
        float score = wave_sum(qrot * kv);
        float mnew  = fmaxf(m, score);
        float alpha = __expf(m - mnew);
        float p     = __expf(score - mnew);
        l   = l * alpha + p;
        acc = acc * alpha + p * vv;
        m   = mnew;
    }
    O[(((size_t)(b * SS + q) * NH) + h) * HD + lane] = acc / l;
}

extern "C" void kernel_launch(void* const* d_in, const int* in_sizes, int n_in,
                              void* d_out, int out_size, void* d_ws, size_t ws_size,
                              hipStream_t stream) {
    const float* Q = (const float*)d_in[0];
    const float* K = (const float*)d_in[1];
    const float* V = (const float*)d_in[2];
    float* O = (float*)d_out;

    size_t kv_elems = (size_t)BB * NKVH * SS * HD;   // 2M elements
    size_t need = 2 * kv_elems * sizeof(ushort);     // 8 MB

    if (ws_size >= need) {
        ushort* Kr = (ushort*)d_ws;
        ushort* Vt = Kr + kv_elems;
        prep_kv<<<BB * NKVH * (SS / 32), 256, 0, stream>>>(K, V, Kr, Vt);
        attn_mfma<<<BB * NKVH * (SS / 32), 256, 0, stream>>>(Q, Kr, Vt, O);
    } else {
        attn_scalar<<<(BB * NH * SS) / 4, 256, 0, stream>>>(Q, K, V, O);
    }
}